// Round 6
// baseline (171.110 us; speedup 1.0000x reference)
//
#include <hip/hip_runtime.h>
#include <hip/hip_fp16.h>

// LDPC neural BP decoder, MI355X. Round 16 (= R15 + compile fix).
// R15 failed to COMPILE: __exp2f is a glibc-internal name (math.h __MATHCALL
// collision), not a HIP device intrinsic. Fixed with
// __builtin_amdgcn_exp2f (direct v_exp_f32, which natively computes 2^x).
// Theory unchanged from R15:
//   LOG-DOMAIN f16-PACKED t-table. enc = copysign(-log2|t|, t) as f16, two
//   rows per u32. Gather becomes ds_read_b32 (64 lanes over 32 banks: avg 2
//   = free per m136, max ~4.4) at HALF the bytes; product -> magnitude SUM;
//   sign product = XOR parity of raw words; check =
//   sign*ln2*(log2(1+q)-log2(1-q)), q=min(2^-L, 0.999999) == reference clip.
//   Precision: f16 err on m is RELATIVE; arctanh sensitivity needs q->1
//   which forces all m->0 where f16 abs err vanishes; ~1e-3/iter on check.
//   Table halves -> LDS 67584 -> 2 blocks/CU, all 512 blocks resident.
// Signature: BANK_CONFLICT 1.7e7 -> ~0.7e7, Occupancy ~70, decode ~55-62us.
// Fallback if absmax fails: f32 table + offline conflict-scheduling of offs.

#define NN    8448
#define MAXNB 10
#define TPB   1024
#define MAXK  9       // ceil(8448/1024)
#define ITERS 5
#define TBL_BYTES  (NN * 4)                 // 33792: u32 per node (2x f16)
#define LDS_BYTES  (2 * TBL_BYTES)          // 67584: double-buffered, static
#define OFFS_INTS  12                       // 10 byte-offs + {wr0,wr1} bits
#define OFFS_BYTES ((size_t)NN * OFFS_INTS * sizeof(int))   // 405504
#define WS_NEEDED  OFFS_BYTES

typedef float v2f __attribute__((ext_vector_type(2)));

__global__ __launch_bounds__(256)
void prep_kernel(const int* __restrict__ cidx, const float* __restrict__ w_res,
                 int* __restrict__ offs)
{
    int n = blockIdx.x * 256 + threadIdx.x;
    if (n < NN) {
        #pragma unroll
        for (int j = 0; j < MAXNB; ++j)
            offs[n * OFFS_INTS + j] = cidx[n * MAXNB + j] * 4;  // byte off of u32
        offs[n * OFFS_INTS + 10] = __float_as_int(w_res[n]);
        offs[n * OFFS_INTS + 11] = __float_as_int(w_res[NN + n]);
    }
}

// enc(v) per row: t = tanh(clip(0.5 v, +-9.9)); m = -log2|t| >= 0;
//   u = exp2(-log2e * min(|v|,19.8)) = e^-z;  m = log2(1+u) - log2(1-u)
//   (since |t| = (1-u)/(1+u)); store copysign(m, v) as f16, rows packed lo/hi.
__device__ __forceinline__ unsigned int enc_pair(v2f v)
{
    float z0 = fminf(fabsf(v.x), 19.8f);
    float z1 = fminf(fabsf(v.y), 19.8f);
    float u0 = __builtin_amdgcn_exp2f(z0 * -1.44269504f);
    float u1 = __builtin_amdgcn_exp2f(z1 * -1.44269504f);
    float m0 = __log2f(1.0f + u0) - __log2f(1.0f - u0);
    float m1 = __log2f(1.0f + u1) - __log2f(1.0f - u1);
    m0 = __builtin_copysignf(m0, v.x);               // v_bfi_b32
    m1 = __builtin_copysignf(m1, v.y);
    unsigned int h0 = __half_as_ushort(__float2half_rn(m0));  // RTN cvt
    unsigned int h1 = __half_as_ushort(__float2half_rn(m1));
    return h0 | (h1 << 16);
}

template<bool USE_OFF>
__global__ __launch_bounds__(TPB)
void ldpc_decode_kernel(const float* __restrict__ input_llr,
                        const float* __restrict__ w_ch,
                        const float* __restrict__ w_res,   // [2][NN]
                        const int*   __restrict__ cidx,    // [NN][10]
                        const int*   __restrict__ offs,    // [NN][12]
                        float* __restrict__ out)
{
    __shared__ __align__(16) char smem[LDS_BYTES];   // 67584 -> 2 blocks/CU
    const int tid  = threadIdx.x;
    const int row0 = blockIdx.x * 2;
    const float* __restrict__ in0 = input_llr + (size_t)row0 * NN;
    const float* __restrict__ in1 = in0 + NN;
    float* __restrict__ out0 = out + (size_t)row0 * NN;
    float* __restrict__ out1 = out0 + NN;

    // persistent state, statically indexed
    v2f wllr[MAXK], vm[MAXK], vmp[MAXK];

    // prologue: init state, write enc(vm) into buffer 0
    #pragma unroll
    for (int k = 0; k < MAXK; ++k) {
        int n = tid + k * TPB;
        wllr[k] = (v2f)(0.0f);
        vmp[k]  = (v2f)(0.0f);
        if (k < MAXK - 1 || n < NN) {
            float wc = w_ch[n];
            v2f x;
            x.x = in0[n];
            x.y = in1[n];
            wllr[k] = x * wc;
        }
        vm[k] = wllr[k];
        if (k < MAXK - 1 || n < NN) {
            *(unsigned int*)(smem + (size_t)n * 4) = enc_pair(vm[k]);
        }
    }
    __syncthreads();

    #pragma unroll
    for (int it = 0; it < ITERS; ++it) {
        const int rbase = (it & 1) ? TBL_BYTES : 0;  // compile-time per it
        const int wbase = (it & 1) ? 0 : TBL_BYTES;
        #pragma unroll
        for (int k = 0; k < MAXK; ++k) {
            int n = tid + k * TPB;
            if (k < MAXK - 1 || n < NN) {
                int o0, o1, o2, o3, o4, o5, o6, o7, o8, o9;
                float wr0, wr1;
                if (USE_OFF) {
                    const int4* op = (const int4*)(offs + n * OFFS_INTS);
                    int4 oA = op[0];                 // rows are 48B, 16-aligned
                    int4 oB = op[1];
                    int4 oC = op[2];
                    o0 = oA.x; o1 = oA.y; o2 = oA.z; o3 = oA.w;
                    o4 = oB.x; o5 = oB.y; o6 = oB.z; o7 = oB.w;
                    o8 = oC.x; o9 = oC.y;
                    wr0 = __int_as_float(oC.z);
                    wr1 = __int_as_float(oC.w);
                } else {
                    const int2* ip = (const int2*)(cidx + n * MAXNB);
                    int2 i0 = ip[0], i1 = ip[1], i2 = ip[2], i3 = ip[3], i4 = ip[4];
                    o0 = i0.x << 2; o1 = i0.y << 2;
                    o2 = i1.x << 2; o3 = i1.y << 2;
                    o4 = i2.x << 2; o5 = i2.y << 2;
                    o6 = i3.x << 2; o7 = i3.y << 2;
                    o8 = i4.x << 2; o9 = i4.y << 2;
                    wr0 = w_res[n];
                    wr1 = w_res[NN + n];
                }
                const char* __restrict__ rb = smem + rbase;
                unsigned int g0 = *(const unsigned int*)(rb + o0);
                unsigned int g1 = *(const unsigned int*)(rb + o1);
                unsigned int g2 = *(const unsigned int*)(rb + o2);
                unsigned int g3 = *(const unsigned int*)(rb + o3);
                unsigned int g4 = *(const unsigned int*)(rb + o4);
                unsigned int g5 = *(const unsigned int*)(rb + o5);
                unsigned int g6 = *(const unsigned int*)(rb + o6);
                unsigned int g7 = *(const unsigned int*)(rb + o7);
                unsigned int g8 = *(const unsigned int*)(rb + o8);
                unsigned int g9 = *(const unsigned int*)(rb + o9);
                // sign product = xor parity (bit15 = row0, bit31 = row1)
                unsigned int xs = ((g0 ^ g1) ^ (g2 ^ g3))
                                ^ ((g4 ^ g5) ^ (g6 ^ g7)) ^ (g8 ^ g9);
                // magnitude sum L = sum of |m| per row (abs = mask both signs)
                #define ABSM(g) ((g) & 0x7fff7fffu)
                unsigned int a0 = ABSM(g0), a1 = ABSM(g1), a2 = ABSM(g2),
                             a3 = ABSM(g3), a4 = ABSM(g4), a5 = ABSM(g5),
                             a6 = ABSM(g6), a7 = ABSM(g7), a8 = ABSM(g8),
                             a9 = ABSM(g9);
                #undef ABSM
                #define LO(a) __half2float(__ushort_as_half((unsigned short)(a)))
                #define HI(a) __half2float(__ushort_as_half((unsigned short)((a) >> 16)))
                float L0 = ((LO(a0) + LO(a1)) + (LO(a2) + LO(a3)))
                         + ((LO(a4) + LO(a5)) + (LO(a6) + LO(a7)))
                         + (LO(a8) + LO(a9));
                float L1 = ((HI(a0) + HI(a1)) + (HI(a2) + HI(a3)))
                         + ((HI(a4) + HI(a5)) + (HI(a6) + HI(a7)))
                         + (HI(a8) + HI(a9));
                #undef LO
                #undef HI
                // |p| = 2^-L, clipped; check = sign * ln2*(log2(1+q)-log2(1-q))
                float q0 = fminf(__builtin_amdgcn_exp2f(-L0), 0.999999f);
                float q1 = fminf(__builtin_amdgcn_exp2f(-L1), 0.999999f);
                float c0 = (__log2f(1.0f + q0) - __log2f(1.0f - q0)) * 0.69314718f;
                float c1 = (__log2f(1.0f + q1) - __log2f(1.0f - q1)) * 0.69314718f;
                c0 = __uint_as_float(__float_as_uint(c0) ^ ((xs << 16) & 0x80000000u));
                c1 = __uint_as_float(__float_as_uint(c1) ^ (xs & 0x80000000u));
                v2f check;
                check.x = c0;
                check.y = c1;
                v2f res = vm[k] * wr0 + vmp[k] * wr1;     // pk_fma
                v2f nv  = (wllr[k] + check) + res;
                vmp[k] = vm[k];
                vm[k]  = nv;
                if (it < ITERS - 1) {
                    *(unsigned int*)(smem + wbase + (size_t)n * 4) = enc_pair(nv);
                }
            }
            // fence: cap per-region register pressure
            __builtin_amdgcn_sched_barrier(0);
        }
        if (it < ITERS - 1) __syncthreads();              // one barrier per iter
    }

    // epilogue: sigmoid(vm + input)
    #pragma unroll
    for (int k = 0; k < MAXK; ++k) {
        int n = tid + k * TPB;
        if (k < MAXK - 1 || n < NN) {
            float x0 = vm[k].x + in0[n];
            float x1 = vm[k].y + in1[n];
            out0[n] = __fdividef(1.0f, 1.0f + __expf(-x0));
            out1[n] = __fdividef(1.0f, 1.0f + __expf(-x1));
        }
    }
}

extern "C" void kernel_launch(void* const* d_in, const int* in_sizes, int n_in,
                              void* d_out, int out_size, void* d_ws, size_t ws_size,
                              hipStream_t stream) {
    const float* input_llr = (const float*)d_in[0];
    const float* w_ch      = (const float*)d_in[1];
    const float* w_res     = (const float*)d_in[2];
    const int*   cidx      = (const int*)d_in[3];
    // d_in[4] (var_index_tensor) is unused by the reference
    float* out = (float*)d_out;
    int batch = in_sizes[0] / NN;
    const bool use_off = (ws_size >= WS_NEEDED) && (d_ws != nullptr);

    if (use_off) {
        int* offs = (int*)d_ws;
        hipLaunchKernelGGL(prep_kernel, dim3((NN + 255) / 256), dim3(256), 0,
                           stream, cidx, w_res, offs);
        hipLaunchKernelGGL(ldpc_decode_kernel<true>, dim3(batch / 2), dim3(TPB),
                           0, stream, input_llr, w_ch, w_res, cidx,
                           offs, out);
    } else {
        hipLaunchKernelGGL(ldpc_decode_kernel<false>, dim3(batch / 2), dim3(TPB),
                           0, stream, input_llr, w_ch, w_res, cidx,
                           nullptr, out);
    }
}

// Round 8
// 161.167 us; speedup vs baseline: 1.0617x; 1.0617x over previous
//
#include <hip/hip_runtime.h>
#include <hip/hip_fp16.h>

// LDPC neural BP decoder, MI355X. Round 18 (= R17 + type fix).
// R17 failed to COMPILE: __builtin_amdgcn_cvt_pkrtz returns
// __fp16 ext_vector(2), not _Float16 ext_vector(2) -> no implicit conv.
// Fix: auto + __builtin_bit_cast to unsigned int. Theory unchanged:
//  - keep halved LDS (u32/node log-domain f16 table, 67584B, 2 blocks/CU)
//  - magnitude sum via 9 v_pk_add_f16 (__hadd2) + 1 unpack (kills R16's
//    +88K cyc/CU VALU regression from 20 cvt + 18 scalar adds)
//  - enc pack via v_cvt_pkrtz_f16_f32 (1 inst both rows)
//  - wllr[] dropped (-18 VGPRs): reload in/w_ch per k (cache-hit, TLP-hidden)
//    -> persistent state 36 regs, peak ~61 < 64 -> no spill at the
//    allocator's immovable 64-VGPR budget
// Predict: VALU busy 168K->~110K cyc/CU, WRITE 42->~34MB, conflicts
// unchanged 1.703e7, decode ~58-68us, total ~120-135us.
// Fallback if absmax fails: f32 adds for sum only.
// Next lever if LDS becomes binding: bank-aware slot permutation in prep
// (check product is order-invariant -> free column permutation of offs).

#define NN    8448
#define MAXNB 10
#define TPB   1024
#define MAXK  9       // ceil(8448/1024)
#define ITERS 5
#define TBL_BYTES  (NN * 4)                 // 33792: u32 per node (2x f16)
#define LDS_BYTES  (2 * TBL_BYTES)          // 67584: double-buffered, static
#define OFFS_INTS  12                       // 10 byte-offs + {wr0,wr1} bits
#define OFFS_BYTES ((size_t)NN * OFFS_INTS * sizeof(int))   // 405504
#define WS_NEEDED  OFFS_BYTES

typedef float v2f __attribute__((ext_vector_type(2)));

__global__ __launch_bounds__(256)
void prep_kernel(const int* __restrict__ cidx, const float* __restrict__ w_res,
                 int* __restrict__ offs)
{
    int n = blockIdx.x * 256 + threadIdx.x;
    if (n < NN) {
        #pragma unroll
        for (int j = 0; j < MAXNB; ++j)
            offs[n * OFFS_INTS + j] = cidx[n * MAXNB + j] * 4;  // byte off of u32
        offs[n * OFFS_INTS + 10] = __float_as_int(w_res[n]);
        offs[n * OFFS_INTS + 11] = __float_as_int(w_res[NN + n]);
    }
}

// enc(v) per row: t = tanh(clip(0.5 v, +-9.9)); m = -log2|t| >= 0;
//   u = exp2(-log2e * min(|v|,19.8)) = e^-z;  m = log2(1+u) - log2(1-u);
//   store copysign(m, v) as f16 pair via one v_cvt_pkrtz_f16_f32.
__device__ __forceinline__ unsigned int enc_pair(v2f v)
{
    float z0 = fminf(fabsf(v.x), 19.8f);
    float z1 = fminf(fabsf(v.y), 19.8f);
    float u0 = __builtin_amdgcn_exp2f(z0 * -1.44269504f);
    float u1 = __builtin_amdgcn_exp2f(z1 * -1.44269504f);
    float m0 = __log2f(1.0f + u0) - __log2f(1.0f - u0);
    float m1 = __log2f(1.0f + u1) - __log2f(1.0f - u1);
    m0 = __builtin_copysignf(m0, v.x);               // v_bfi_b32
    m1 = __builtin_copysignf(m1, v.y);
    auto p = __builtin_amdgcn_cvt_pkrtz(m0, m1);     // 1 inst, both rows
    return __builtin_bit_cast(unsigned int, p);
}

__device__ __forceinline__ __half2 u2h(unsigned int v)
{
    return __builtin_bit_cast(__half2, v);
}

template<bool USE_OFF>
__global__ __launch_bounds__(TPB)
void ldpc_decode_kernel(const float* __restrict__ input_llr,
                        const float* __restrict__ w_ch,
                        const float* __restrict__ w_res,   // [2][NN]
                        const int*   __restrict__ cidx,    // [NN][10]
                        const int*   __restrict__ offs,    // [NN][12]
                        float* __restrict__ out)
{
    __shared__ __align__(16) char smem[LDS_BYTES];   // 67584 -> 2 blocks/CU
    const int tid  = threadIdx.x;
    const int row0 = blockIdx.x * 2;
    const float* __restrict__ in0 = input_llr + (size_t)row0 * NN;
    const float* __restrict__ in1 = in0 + NN;
    float* __restrict__ out0 = out + (size_t)row0 * NN;
    float* __restrict__ out1 = out0 + NN;

    // persistent state: vm/vmp only (36 VGPRs); wllr recomputed from inputs
    v2f vm[MAXK], vmp[MAXK];

    // prologue: init state, write enc(vm) into buffer 0
    #pragma unroll
    for (int k = 0; k < MAXK; ++k) {
        int n = tid + k * TPB;
        vmp[k] = (v2f)(0.0f);
        vm[k]  = (v2f)(0.0f);
        if (k < MAXK - 1 || n < NN) {
            float wc = w_ch[n];
            v2f x;
            x.x = in0[n];
            x.y = in1[n];
            vm[k] = x * wc;
            *(unsigned int*)(smem + (size_t)n * 4) = enc_pair(vm[k]);
        }
    }
    __syncthreads();

    #pragma unroll
    for (int it = 0; it < ITERS; ++it) {
        const int rbase = (it & 1) ? TBL_BYTES : 0;  // compile-time per it
        const int wbase = (it & 1) ? 0 : TBL_BYTES;
        #pragma unroll
        for (int k = 0; k < MAXK; ++k) {
            int n = tid + k * TPB;
            if (k < MAXK - 1 || n < NN) {
                int o0, o1, o2, o3, o4, o5, o6, o7, o8, o9;
                float wr0, wr1;
                if (USE_OFF) {
                    const int4* op = (const int4*)(offs + n * OFFS_INTS);
                    int4 oA = op[0];                 // rows are 48B, 16-aligned
                    int4 oB = op[1];
                    int4 oC = op[2];
                    o0 = oA.x; o1 = oA.y; o2 = oA.z; o3 = oA.w;
                    o4 = oB.x; o5 = oB.y; o6 = oB.z; o7 = oB.w;
                    o8 = oC.x; o9 = oC.y;
                    wr0 = __int_as_float(oC.z);
                    wr1 = __int_as_float(oC.w);
                } else {
                    const int2* ip = (const int2*)(cidx + n * MAXNB);
                    int2 i0 = ip[0], i1 = ip[1], i2 = ip[2], i3 = ip[3], i4 = ip[4];
                    o0 = i0.x << 2; o1 = i0.y << 2;
                    o2 = i1.x << 2; o3 = i1.y << 2;
                    o4 = i2.x << 2; o5 = i2.y << 2;
                    o6 = i3.x << 2; o7 = i3.y << 2;
                    o8 = i4.x << 2; o9 = i4.y << 2;
                    wr0 = w_res[n];
                    wr1 = w_res[NN + n];
                }
                const char* __restrict__ rb = smem + rbase;
                unsigned int g0 = *(const unsigned int*)(rb + o0);
                unsigned int g1 = *(const unsigned int*)(rb + o1);
                unsigned int g2 = *(const unsigned int*)(rb + o2);
                unsigned int g3 = *(const unsigned int*)(rb + o3);
                unsigned int g4 = *(const unsigned int*)(rb + o4);
                unsigned int g5 = *(const unsigned int*)(rb + o5);
                unsigned int g6 = *(const unsigned int*)(rb + o6);
                unsigned int g7 = *(const unsigned int*)(rb + o7);
                unsigned int g8 = *(const unsigned int*)(rb + o8);
                unsigned int g9 = *(const unsigned int*)(rb + o9);
                // sign product = xor parity (bit15 = row0, bit31 = row1)
                unsigned int xs = ((g0 ^ g1) ^ (g2 ^ g3))
                                ^ ((g4 ^ g5) ^ (g6 ^ g7)) ^ (g8 ^ g9);
                // magnitude sum: mask signs, 9 packed f16 adds, unpack once
                __half2 s = __hadd2(
                    __hadd2(__hadd2(u2h(g0 & 0x7fff7fffu), u2h(g1 & 0x7fff7fffu)),
                            __hadd2(u2h(g2 & 0x7fff7fffu), u2h(g3 & 0x7fff7fffu))),
                    __hadd2(
                        __hadd2(__hadd2(u2h(g4 & 0x7fff7fffu), u2h(g5 & 0x7fff7fffu)),
                                __hadd2(u2h(g6 & 0x7fff7fffu), u2h(g7 & 0x7fff7fffu))),
                        __hadd2(u2h(g8 & 0x7fff7fffu), u2h(g9 & 0x7fff7fffu))));
                float L0 = __half2float(__low2half(s));
                float L1 = __half2float(__high2half(s));
                // |p| = 2^-L, clipped; check = sign * ln2*(log2(1+q)-log2(1-q))
                float q0 = fminf(__builtin_amdgcn_exp2f(-L0), 0.999999f);
                float q1 = fminf(__builtin_amdgcn_exp2f(-L1), 0.999999f);
                float c0 = (__log2f(1.0f + q0) - __log2f(1.0f - q0)) * 0.69314718f;
                float c1 = (__log2f(1.0f + q1) - __log2f(1.0f - q1)) * 0.69314718f;
                c0 = __uint_as_float(__float_as_uint(c0) ^ ((xs << 16) & 0x80000000u));
                c1 = __uint_as_float(__float_as_uint(c1) ^ (xs & 0x80000000u));
                // nv = in*wc + check + wr0*vm + wr1*vmp  (wllr recomputed)
                float wc = w_ch[n];
                v2f x;
                x.x = in0[n];
                x.y = in1[n];
                v2f check;
                check.x = c0;
                check.y = c1;
                v2f res = vm[k] * wr0 + vmp[k] * wr1;     // pk_fma
                v2f nv  = (x * wc + check) + res;
                vmp[k] = vm[k];
                vm[k]  = nv;
                if (it < ITERS - 1) {
                    *(unsigned int*)(smem + wbase + (size_t)n * 4) = enc_pair(nv);
                }
            }
            // fence: cap per-region register pressure
            __builtin_amdgcn_sched_barrier(0);
        }
        if (it < ITERS - 1) __syncthreads();              // one barrier per iter
    }

    // epilogue: sigmoid(vm + input)
    #pragma unroll
    for (int k = 0; k < MAXK; ++k) {
        int n = tid + k * TPB;
        if (k < MAXK - 1 || n < NN) {
            float x0 = vm[k].x + in0[n];
            float x1 = vm[k].y + in1[n];
            out0[n] = __fdividef(1.0f, 1.0f + __expf(-x0));
            out1[n] = __fdividef(1.0f, 1.0f + __expf(-x1));
        }
    }
}

extern "C" void kernel_launch(void* const* d_in, const int* in_sizes, int n_in,
                              void* d_out, int out_size, void* d_ws, size_t ws_size,
                              hipStream_t stream) {
    const float* input_llr = (const float*)d_in[0];
    const float* w_ch      = (const float*)d_in[1];
    const float* w_res     = (const float*)d_in[2];
    const int*   cidx      = (const int*)d_in[3];
    // d_in[4] (var_index_tensor) is unused by the reference
    float* out = (float*)d_out;
    int batch = in_sizes[0] / NN;
    const bool use_off = (ws_size >= WS_NEEDED) && (d_ws != nullptr);

    if (use_off) {
        int* offs = (int*)d_ws;
        hipLaunchKernelGGL(prep_kernel, dim3((NN + 255) / 256), dim3(256), 0,
                           stream, cidx, w_res, offs);
        hipLaunchKernelGGL(ldpc_decode_kernel<true>, dim3(batch / 2), dim3(TPB),
                           0, stream, input_llr, w_ch, w_res, cidx,
                           offs, out);
    } else {
        hipLaunchKernelGGL(ldpc_decode_kernel<false>, dim3(batch / 2), dim3(TPB),
                           0, stream, input_llr, w_ch, w_res, cidx,
                           nullptr, out);
    }
}